// Round 2
// baseline (1018.826 us; speedup 1.0000x reference)
//
#include <hip/hip_runtime.h>
#include <cstdint>

// Net_79139067396690: MC-dropout moment-propagation MLP.
//   h   = relu(0.5*x@W1^T + sqrt(0.25*(x^2)@(W1^2)^T) * eps1/sqrt(1000))
//   out =      0.5*h@W2^T + sqrt(0.25*(h^2)@(W2^2)^T) * eps2/sqrt(1000)
// eps = jax.random.normal reproduced bit-exactly, PARTITIONABLE threefry:
//   bits[i] = o0 ^ o1 of threefry2x32(key, hi32(i)=0, lo32(i)=i)
//   split(key)[j] = (o0, o1) of threefry2x32(key, 0, j)

#define NB 65536
#define DIN 784
#define HD 256
#define CD 10

// ---- Threefry-2x32, JAX-compatible (20 rounds, 5x4, key schedule every 4) ----
__host__ __device__ inline void threefry2x32(uint32_t k0, uint32_t k1,
                                             uint32_t x0, uint32_t x1,
                                             uint32_t& o0, uint32_t& o1) {
  uint32_t ks[3] = {k0, k1, k0 ^ k1 ^ 0x1BD11BDAu};
  x0 += ks[0];
  x1 += ks[1];
  const uint32_t rot[8] = {13u, 15u, 26u, 6u, 17u, 29u, 16u, 24u};
#pragma unroll
  for (int i = 0; i < 5; ++i) {
#pragma unroll
    for (int j = 0; j < 4; ++j) {
      uint32_t r = rot[(i & 1) * 4 + j];
      x0 += x1;
      x1 = (x1 << r) | (x1 >> (32u - r));
      x1 ^= x0;
    }
    x0 += ks[(i + 1) % 3];
    x1 += ks[(i + 2) % 3] + (uint32_t)(i + 1);
  }
  o0 = x0;
  o1 = x1;
}

// bits -> N(0,1) draw, matching jax.random.normal's pipeline:
//   u01 = bitcast((bits>>9)|0x3F800000) - 1          in [0,1)
//   u   = max(lo, u01*(hi-lo) + lo), lo = nextafter(-1,0); (hi-lo) rounds to 2.0f
//   eps = sqrt(2) * erfinv(u)   (XLA/Giles f32 polynomial)
__device__ inline float bits_to_normal(uint32_t bits) {
  const float lo = -0.99999994f;  // nextafterf(-1,0)
  float u01 = __uint_as_float((bits >> 9) | 0x3F800000u) - 1.0f;
  float u = fmaxf(lo, u01 * 2.0f + lo);
  float w = -log1pf(-u * u);
  float p;
  if (w < 5.0f) {
    w -= 2.5f;
    p = 2.81022636e-08f;
    p = fmaf(p, w, 3.43273939e-07f);
    p = fmaf(p, w, -3.5233877e-06f);
    p = fmaf(p, w, -4.39150654e-06f);
    p = fmaf(p, w, 0.00021858087f);
    p = fmaf(p, w, -0.00125372503f);
    p = fmaf(p, w, -0.00417768164f);
    p = fmaf(p, w, 0.246640727f);
    p = fmaf(p, w, 1.50140941f);
  } else {
    w = sqrtf(w) - 3.0f;
    p = -0.000200214257f;
    p = fmaf(p, w, 0.000100950558f);
    p = fmaf(p, w, 0.00134934322f);
    p = fmaf(p, w, -0.00367342844f);
    p = fmaf(p, w, 0.00573950773f);
    p = fmaf(p, w, -0.0076224613f);
    p = fmaf(p, w, 0.00943887047f);
    p = fmaf(p, w, 1.00167406f);
    p = fmaf(p, w, 2.83297682f);
  }
  return 1.41421356f * (p * u);
}

// partitionable random_bits for flat index i (array size < 2^32 -> hi = 0)
__device__ inline float eps_partitionable(uint32_t ka, uint32_t kb, uint32_t i) {
  uint32_t o0, o1;
  threefry2x32(ka, kb, 0u, i, o0, o1);
  return bits_to_normal(o0 ^ o1);
}

// Fused kernel: one block = 32 batch rows, computes full h[32][256] then out[32][10].
// LDS: smem = A[32][17] + B[256][17] during K-loop, reused as H[32][257] after.
__global__ __launch_bounds__(256) void fused_net(
    const float* __restrict__ x, const float* __restrict__ W1,
    const float* __restrict__ W2, float* __restrict__ out,
    uint32_t k1a, uint32_t k1b, uint32_t k2a, uint32_t k2b) {
  __shared__ float smem[32 * 257];   // 32.9 KB (A+B phase needs only 4896 floats)
  __shared__ float sW2[10 * 260];    // stride 260 breaks the 10-way bank conflict

  const int tid = threadIdx.x;
  const int tx = tid & 15;   // col group
  const int ty = tid >> 4;   // row pair
  const int gr0 = blockIdx.x * 32;

  // stage W2 once (2560 floats, coalesced)
#pragma unroll
  for (int j = 0; j < 10; ++j) {
    int g = tid + j * 256;
    sW2[(g >> 8) * 260 + (g & 255)] = W2[g];
  }

  float* sA = smem;             // [32][17]
  float* sB = smem + 32 * 17;   // [256][17]

  float m0[16], m1[16], v0[16], v1[16];
#pragma unroll
  for (int j = 0; j < 16; ++j) { m0[j] = m1[j] = v0[j] = v1[j] = 0.0f; }

  for (int kk = 0; kk < DIN; kk += 16) {
    __syncthreads();
    // stage A tile: 32 rows x 16 k = 512 f32; threads 0..127 load one float4
    if (tid < 128) {
      int row = tid >> 2, q = tid & 3;
      const float4 va = *reinterpret_cast<const float4*>(
          &x[(size_t)(gr0 + row) * DIN + kk + q * 4]);
      float* dst = &sA[row * 17 + q * 4];
      dst[0] = va.x; dst[1] = va.y; dst[2] = va.z; dst[3] = va.w;
    }
    // stage B tile: 256 rows x 16 k = 4096 f32 = 1024 float4, 4 per thread
#pragma unroll
    for (int i = 0; i < 4; ++i) {
      int f = tid + i * 256;
      int row = f >> 2, q = f & 3;
      const float4 vb = *reinterpret_cast<const float4*>(
          &W1[(size_t)row * DIN + kk + q * 4]);
      float* dst = &sB[row * 17 + q * 4];
      dst[0] = vb.x; dst[1] = vb.y; dst[2] = vb.z; dst[3] = vb.w;
    }
    __syncthreads();
#pragma unroll 4
    for (int k = 0; k < 16; ++k) {
      float a0 = sA[(ty * 2) * 17 + k];
      float a1 = sA[(ty * 2 + 1) * 17 + k];
      float a0s = a0 * a0, a1s = a1 * a1;
#pragma unroll
      for (int j = 0; j < 16; ++j) {
        float b = sB[(tx + 16 * j) * 17 + k];
        float bs = b * b;
        m0[j] = fmaf(a0, b, m0[j]);
        v0[j] = fmaf(a0s, bs, v0[j]);
        m1[j] = fmaf(a1, b, m1[j]);
        v1[j] = fmaf(a1s, bs, v1[j]);
      }
    }
  }
  __syncthreads();

  // layer-1 epilogue: eps1 + relu -> sH (aliases the A/B region)
  const float sqrtZ = 31.622776601683793f;  // f32 sqrt(1000)
  float (*sH)[257] = (float(*)[257])smem;
#pragma unroll
  for (int i = 0; i < 2; ++i) {
    int rl = ty * 2 + i;
    int r = gr0 + rl;
#pragma unroll
    for (int j = 0; j < 16; ++j) {
      int c = tx + 16 * j;
      float acc_m = (i == 0) ? m0[j] : m1[j];
      float acc_v = (i == 0) ? v0[j] : v1[j];
      float mean = 0.5f * acc_m;
      float sd = sqrtf(0.25f * acc_v);
      uint32_t idx = (uint32_t)r * 256u + (uint32_t)c;
      float eps = eps_partitionable(k1a, k1b, idx);
      float h = mean + sd * (eps / sqrtZ);
      sH[rl][c] = fmaxf(h, 0.0f);
    }
  }
  __syncthreads();

  // layer 2: 32 rows x 10 cols = 320 items over 256 threads
#pragma unroll
  for (int it = 0; it < 2; ++it) {
    int item = tid + it * 256;
    if (item < 320) {
      int rl = item / 10, c = item % 10;
      int r = gr0 + rl;
      float m = 0.0f, v = 0.0f;
#pragma unroll 8
      for (int k = 0; k < 256; ++k) {
        float hh = sH[rl][k];
        float ww = sW2[c * 260 + k];
        m = fmaf(hh, ww, m);
        v = fmaf(hh * hh, ww * ww, v);
      }
      float mean = 0.5f * m;
      float sd = sqrtf(0.25f * v);
      uint32_t idx = (uint32_t)r * 10u + (uint32_t)c;
      float eps = eps_partitionable(k2a, k2b, idx);
      out[(size_t)r * CD + c] = mean + sd * (eps / sqrtZ);
    }
  }
}

extern "C" void kernel_launch(void* const* d_in, const int* in_sizes, int n_in,
                              void* d_out, int out_size, void* d_ws, size_t ws_size,
                              hipStream_t stream) {
  const float* x = (const float*)d_in[0];
  const float* W1 = (const float*)d_in[1];
  const float* W2 = (const float*)d_in[2];
  float* outp = (float*)d_out;

  // k1, k2 = jax.random.split(jax.random.key(42)) with threefry_partitionable:
  // key_j = (o0, o1) of threefry2x32(key=(0,42), counts=(0, j))
  uint32_t k1a, k1b, k2a, k2b;
  threefry2x32(0u, 42u, 0u, 0u, k1a, k1b);
  threefry2x32(0u, 42u, 0u, 1u, k2a, k2b);

  fused_net<<<NB / 32, 256, 0, stream>>>(x, W1, W2, outp, k1a, k1b, k2a, k2b);
}

// Round 3
// 741.892 us; speedup vs baseline: 1.3733x; 1.3733x over previous
//
#include <hip/hip_runtime.h>
#include <cstdint>

// Net_79139067396690: MC-dropout moment-propagation MLP, MFMA version.
//   h   = relu(0.5*x@W1^T + 0.5*sqrt((x^2)@(W1^2)^T) * eps1/sqrt(1000))
//   out =      0.5*h@W2^T + 0.5*sqrt((h^2)@(W2^2)^T) * eps2/sqrt(1000)
// GEMM1 on bf16 matrix cores (16x16x32), layer 2 + RNG on VALU.
// eps = jax.random.normal, partitionable threefry (verified in round 2).

#define K_DIM 784
#define KP 800                 // K padded to multiple of 32 in the W1 pack
#define N_HID 256
#define N_OUT 10
#define BM 128
#define NSTEP 25               // KP/32
#define WSQ_OFF (N_HID * KP)   // ushort offset of squared-W pack

using short8 = __attribute__((ext_vector_type(8))) short;
using floatx4 = __attribute__((ext_vector_type(4))) float;
typedef uint16_t u16;

// ---- Threefry-2x32 (JAX-compatible) ----
__host__ __device__ inline void threefry2x32(uint32_t k0, uint32_t k1,
                                             uint32_t x0, uint32_t x1,
                                             uint32_t& o0, uint32_t& o1) {
  uint32_t ks[3] = {k0, k1, k0 ^ k1 ^ 0x1BD11BDAu};
  x0 += ks[0];
  x1 += ks[1];
  const uint32_t rot[8] = {13u, 15u, 26u, 6u, 17u, 29u, 16u, 24u};
#pragma unroll
  for (int i = 0; i < 5; ++i) {
#pragma unroll
    for (int j = 0; j < 4; ++j) {
      uint32_t r = rot[(i & 1) * 4 + j];
      x0 += x1;
      x1 = (x1 << r) | (x1 >> (32u - r));
      x1 ^= x0;
    }
    x0 += ks[(i + 1) % 3];
    x1 += ks[(i + 2) % 3] + (uint32_t)(i + 1);
  }
  o0 = x0;
  o1 = x1;
}

// bits -> N(0,1), matching jax.random.normal (mantissa-uniform + Giles erfinv)
__device__ __forceinline__ float bits_to_normal(uint32_t bits) {
  const float lo = -0.99999994f;  // nextafterf(-1,0)
  float u01 = __uint_as_float((bits >> 9) | 0x3F800000u) - 1.0f;
  float u = fmaxf(lo, u01 * 2.0f + lo);
  float w = -log1pf(-u * u);
  float p;
  if (w < 5.0f) {
    w -= 2.5f;
    p = 2.81022636e-08f;
    p = fmaf(p, w, 3.43273939e-07f);
    p = fmaf(p, w, -3.5233877e-06f);
    p = fmaf(p, w, -4.39150654e-06f);
    p = fmaf(p, w, 0.00021858087f);
    p = fmaf(p, w, -0.00125372503f);
    p = fmaf(p, w, -0.00417768164f);
    p = fmaf(p, w, 0.246640727f);
    p = fmaf(p, w, 1.50140941f);
  } else {
    w = sqrtf(w) - 3.0f;
    p = -0.000200214257f;
    p = fmaf(p, w, 0.000100950558f);
    p = fmaf(p, w, 0.00134934322f);
    p = fmaf(p, w, -0.00367342844f);
    p = fmaf(p, w, 0.00573950773f);
    p = fmaf(p, w, -0.0076224613f);
    p = fmaf(p, w, 0.00943887047f);
    p = fmaf(p, w, 1.00167406f);
    p = fmaf(p, w, 2.83297682f);
  }
  return 1.41421356f * (p * u);
}

__device__ __forceinline__ float eps_part(uint32_t ka, uint32_t kb, uint32_t i) {
  uint32_t o0, o1;
  threefry2x32(ka, kb, 0u, i, o0, o1);
  return bits_to_normal(o0 ^ o1);
}

// f32 -> bf16 with round-to-nearest-even (no NaN inputs here)
__host__ __device__ __forceinline__ u16 f2bf(float f) {
  uint32_t u;
#ifdef __HIP_DEVICE_COMPILE__
  u = __float_as_uint(f);
#else
  __builtin_memcpy(&u, &f, 4);
#endif
  return (u16)((u + 0x7FFFu + ((u >> 16) & 1u)) >> 16);
}

// ---- pre-pack W1 -> bf16 {w, w^2}, K padded to 800 with zeros ----
__global__ __launch_bounds__(256) void pack_w1(const float* __restrict__ W1,
                                               u16* __restrict__ bp) {
  const int col = blockIdx.x;  // 0..255
  for (int k = threadIdx.x; k < KP; k += 256) {
    float w = (k < K_DIM) ? W1[col * K_DIM + k] : 0.0f;
    bp[col * KP + k] = f2bf(w);
    bp[WSQ_OFF + col * KP + k] = f2bf(w * w);
  }
}

// ---- fused main kernel: one block = 128 batch rows, full N=256 ----
__global__ __launch_bounds__(512, 2) void fused_mfma(
    const float* __restrict__ x, const u16* __restrict__ bp,
    const float* __restrict__ W2, float* __restrict__ out,
    uint32_t k1a, uint32_t k1b, uint32_t k2a, uint32_t k2b) {
  __shared__ u16 sA[2][2][BM * 32];  // [dbuf][tensor: x, x^2][swizzled row*32+k]
  __shared__ u16 hbuf[BM * 258];     // h (bf16), row stride 258 breaks conflicts
  __shared__ float sW2[10 * 260];

  const int tid = threadIdx.x;
  const int lane = tid & 63;
  const int l15 = lane & 15;
  const int lhal = lane >> 4;  // 0..3
  const int wid = tid >> 6;    // 0..7
  const int wm = wid >> 2;     // 0..1  (m-direction)
  const int wn = wid & 3;      // 0..3  (n-direction)
  const int gr0 = blockIdx.x * BM;

  // --- staging geometry: thread -> (row, 8-wide k chunk) of the A tile ---
  const int srow = tid >> 2;         // 0..127
  const int skq = (tid & 3) * 8;     // 0,8,16,24
  const float* xptr = x + (size_t)(gr0 + srow) * K_DIM + skq;
  const int sidx = (srow * 32 + skq) ^ ((srow & 7) << 3);  // XOR swizzle (u16 units)

  // --- per-wave B addressing into the bf16 pack (direct global, L2-hot) ---
  size_t bbase[4];
#pragma unroll
  for (int j = 0; j < 4; ++j) {
    int col = wn * 64 + j * 16 + l15;
    bbase[j] = (size_t)col * KP + lhal * 8;
  }

  // --- per-wave A fragment LDS indices ---
  int aidx[4];
#pragma unroll
  for (int i = 0; i < 4; ++i) {
    int r = wm * 64 + i * 16 + l15;
    aidx[i] = (r * 32 + lhal * 8) ^ ((r & 7) << 3);
  }

  floatx4 accm[4][4], accv[4][4];
#pragma unroll
  for (int i = 0; i < 4; ++i)
#pragma unroll
    for (int j = 0; j < 4; ++j)
#pragma unroll
      for (int g = 0; g < 4; ++g) { accm[i][j][g] = 0.0f; accv[i][j][g] = 0.0f; }

  float4 q0, q1;
  auto loadX = [&](int kk) {
    if (kk + skq + 8 <= K_DIM) {  // K tail (784 = 24*32+16): zero-fill OOB chunks
      q0 = *reinterpret_cast<const float4*>(xptr + kk);
      q1 = *reinterpret_cast<const float4*>(xptr + kk + 4);
    } else {
      q0 = make_float4(0.f, 0.f, 0.f, 0.f);
      q1 = make_float4(0.f, 0.f, 0.f, 0.f);
    }
  };
  auto writeA = [&](int buf) {
    const float f[8] = {q0.x, q0.y, q0.z, q0.w, q1.x, q1.y, q1.z, q1.w};
    short8 va, v2;
#pragma unroll
    for (int i = 0; i < 8; ++i) {
      va[i] = (short)f2bf(f[i]);
      v2[i] = (short)f2bf(f[i] * f[i]);
    }
    *reinterpret_cast<short8*>(&sA[buf][0][sidx]) = va;
    *reinterpret_cast<short8*>(&sA[buf][1][sidx]) = v2;
  };

  short8 bmc[4], bvc[4], bmn[4], bvn[4];
  auto loadB = [&](int kk, short8* bm, short8* bv) {
#pragma unroll
    for (int j = 0; j < 4; ++j) {
      bm[j] = *reinterpret_cast<const short8*>(&bp[bbase[j] + kk]);
      bv[j] = *reinterpret_cast<const short8*>(&bp[WSQ_OFF + bbase[j] + kk]);
    }
  };

  // prologue: stage step 0
  loadX(0);
  writeA(0);
  loadB(0, bmc, bvc);
  __syncthreads();

  for (int s = 0; s < NSTEP; ++s) {
    const int cur = s & 1, nxt = cur ^ 1;
    const bool have = (s + 1 < NSTEP);
    if (have) {               // prefetch next tile (global) before the MFMAs
      loadX((s + 1) * 32);
      loadB((s + 1) * 32, bmn, bvn);
    }
    short8 af[4], avf[4];
#pragma unroll
    for (int i = 0; i < 4; ++i) {
      af[i] = *reinterpret_cast<const short8*>(&sA[cur][0][aidx[i]]);
      avf[i] = *reinterpret_cast<const short8*>(&sA[cur][1][aidx[i]]);
    }
#pragma unroll
    for (int i = 0; i < 4; ++i)
#pragma unroll
      for (int j = 0; j < 4; ++j) {
        accm[i][j] = __builtin_amdgcn_mfma_f32_16x16x32_bf16(af[i], bmc[j], accm[i][j], 0, 0, 0);
        accv[i][j] = __builtin_amdgcn_mfma_f32_16x16x32_bf16(avf[i], bvc[j], accv[i][j], 0, 0, 0);
      }
    if (have) writeA(nxt);    // convert + ds_write for next step
    __syncthreads();
    if (have) {
#pragma unroll
      for (int j = 0; j < 4; ++j) { bmc[j] = bmn[j]; bvc[j] = bvn[j]; }
    }
  }

  // --- stage W2 (f32) ---
#pragma unroll
  for (int g = 0; g < 5; ++g) {
    int gg = tid + g * 512;  // 2560 = 5*512 exactly
    sW2[(gg >> 8) * 260 + (gg & 255)] = W2[gg];
  }

  // --- layer-1 epilogue: eps1 + relu -> hbuf (bf16) ---
  const float INV = 0.031622776601683794f;  // 1/sqrt(1000)
#pragma unroll
  for (int i = 0; i < 4; ++i)
#pragma unroll
    for (int j = 0; j < 4; ++j)
#pragma unroll
      for (int g = 0; g < 4; ++g) {
        int rl = wm * 64 + i * 16 + lhal * 4 + g;  // C/D: row=(lane>>4)*4+reg
        int c = wn * 64 + j * 16 + l15;            //      col=lane&15
        float mean = 0.5f * accm[i][j][g];
        float sd = 0.5f * sqrtf(accv[i][j][g]);
        uint32_t idx = (uint32_t)(gr0 + rl) * 256u + (uint32_t)c;
        float eps = eps_part(k1a, k1b, idx);
        float h = fmaxf(mean + sd * (eps * INV), 0.0f);
        hbuf[rl * 258 + c] = f2bf(h);
      }
  __syncthreads();

  // --- layer 2 (VALU): 128x10 outputs, K=256 from hbuf ---
#pragma unroll
  for (int it = 0; it < 3; ++it) {
    int item = tid + it * 512;
    if (item < BM * N_OUT) {
      int rl = item / N_OUT;
      int c = item - rl * N_OUT;
      float m = 0.0f, v = 0.0f;
#pragma unroll 8
      for (int k = 0; k < N_HID; ++k) {
        float hh = __uint_as_float((uint32_t)hbuf[rl * 258 + k] << 16);
        float w = sW2[c * 260 + k];
        m = fmaf(hh, w, m);
        v = fmaf(hh * hh, w * w, v);
      }
      float mean = 0.5f * m;
      float sd = 0.5f * sqrtf(v);
      uint32_t idx = (uint32_t)(gr0 + rl) * 10u + (uint32_t)c;
      float eps = eps_part(k2a, k2b, idx);
      out[(size_t)(gr0 + rl) * N_OUT + c] = mean + sd * (eps * INV);
    }
  }
}

extern "C" void kernel_launch(void* const* d_in, const int* in_sizes, int n_in,
                              void* d_out, int out_size, void* d_ws, size_t ws_size,
                              hipStream_t stream) {
  const float* x = (const float*)d_in[0];
  const float* W1 = (const float*)d_in[1];
  const float* W2 = (const float*)d_in[2];
  float* outp = (float*)d_out;
  u16* bp = (u16*)d_ws;  // needs 2*256*800*2 = 819200 B

  // k1, k2 = jax.random.split(jax.random.key(42)), partitionable threefry
  uint32_t k1a, k1b, k2a, k2b;
  threefry2x32(0u, 42u, 0u, 0u, k1a, k1b);
  threefry2x32(0u, 42u, 0u, 1u, k2a, k2b);

  pack_w1<<<256, 256, 0, stream>>>(W1, bp);
  fused_mfma<<<65536 / BM, 512, 0, stream>>>(x, bp, W2, outp, k1a, k1b, k2a, k2b);
}